// Round 11
// baseline (27.182 us; speedup 1.0000x reference)
//
#include <hip/hip_runtime.h>

#define NPTS 4096
#define BATCH 8
#define BIGF 1e10f

typedef __attribute__((ext_vector_type(8))) short short8;    // 8 bf16 = 4 VGPR (32x32x16 A/B frag)
typedef __attribute__((ext_vector_type(16))) float f32x16;   // 32x32 C/D frag
typedef unsigned short us;

__device__ __forceinline__ us f2bf(float f) {                // RNE bf16 (unbiased)
    unsigned u = __float_as_uint(f);
    return (us)((u + 0x7FFFu + ((u >> 16) & 1u)) >> 16);
}
__device__ __forceinline__ float bff(us s) { return __uint_as_float(((unsigned)s) << 16); }
__device__ __forceinline__ void split2(float v, us* h, us* m) {
    *h = f2bf(v); *m = f2bf(v - bff(*h));                    // 2-way split, err ~2^-17 |v|
}
__device__ __forceinline__ unsigned pk2(us a, us b) { return (unsigned)a | ((unsigned)b << 16); }

// K=16 pairing (13 live slots, HW-verified absmax ~0 in R10):
//  dot = x2 + w - 2 x.y  (dropped tm*bm term ~2^-17|2xy|)
__device__ __forceinline__ void apackA(float x, float y, float z,
                                       uint4* __restrict__ dst, int row) {
    const us one = 0x3F80;
    us thx,tmx, thy,tmy, thz,tmz, x2h,x2m;
    split2(-2.f*x, &thx,&tmx);
    split2(-2.f*y, &thy,&tmy);
    split2(-2.f*z, &thz,&tmz);
    split2(x*x + y*y + z*z, &x2h,&x2m);
    dst[row]      = make_uint4(pk2(thx,thy), pk2(thz,thx), pk2(thy,thz), pk2(tmx,tmy));
    dst[row + 32] = make_uint4(pk2(tmz,x2h), pk2(x2m,one), pk2(one,0),   pk2(0,0));
}

__device__ __forceinline__ void bpackB(
    const float* __restrict__ points, const float* __restrict__ bres,
    const int* __restrict__ mask, int g, uint4* __restrict__ dst, int col)
{
    float x = points[g*3+0] + bres[g*3+0];
    float y = points[g*3+1] + bres[g*3+1];
    float z = points[g*3+2] + bres[g*3+2];
    float wq = x*x + y*y + z*z + (mask[g] ? 0.f : BIGF);     // col-side mask penalty
    const us one = 0x3F80;
    us bhx,bmx, bhy,bmy, bhz,bmz, wh,wm;
    split2(x, &bhx,&bmx);
    split2(y, &bhy,&bmy);
    split2(z, &bhz,&bmz);
    split2(wq, &wh,&wm);
    dst[col]      = make_uint4(pk2(bhx,bhy), pk2(bhz,bmx), pk2(bmy,bmz), pk2(bhx,bhy));
    dst[col + 32] = make_uint4(pk2(bhz,one), pk2(one,wh),  pk2(wm,0),    pk2(0,0));
}

// Single fused kernel, 32x32x16 MFMA, 2 row-tiles per wave.
// Block = (dir, b, 256-row strip); 8 waves. Wave w: row-tiles {2*(w&3), 2*(w&3)+1}
// (64 rows), col-half (w>>2) of each 512-col chunk (8 col-tiles). Each B-frag
// read feeds 2 MFMAs = 2048 outputs -> LDS return traffic halved vs R10.
// Row-half mins combined via 2KB LDS, then masked sum -> one atomicAdd.
__global__ __launch_bounds__(512) void fused_kernel(
    const float* __restrict__ pred, const float* __restrict__ target,
    const int* __restrict__ mask, const float* __restrict__ points,
    float* __restrict__ out)
{
    __shared__ uint4 Bsh[2][16][64];   // 2 x 16KB: 16 col-tiles per chunk
    __shared__ uint4 Ash[8][64];       // 8KB: 8 row-tiles (256 rows)
    __shared__ float smin[256][2];     // per-row min from each col-half
    __shared__ float scnt[8], swave[8];

    int bid = blockIdx.x;              // 256 = 2 dir x 8 b x 16 strips
    int strip = bid & 15, b = (bid >> 4) & 7, dir = bid >> 7;
    int t = threadIdx.x, w = t >> 6, lane = t & 63;
    int wq = w & 3;                    // row-quad (which 64 rows)
    int wh = w >> 2;                   // col-half

    const float* __restrict__ ares = dir ? pred : target;    // rows: dir0=clean, dir1=predp
    const float* __restrict__ bres = dir ? target : pred;    // cols: dir0=predp, dir1=clean

    // A-prep: this block's 256 row points (threads 0..255)
    if (t < 256) {
        int g = b * NPTS + strip * 256 + t;
        float x = points[g*3+0] + ares[g*3+0];
        float y = points[g*3+1] + ares[g*3+1];
        float z = points[g*3+2] + ares[g*3+2];
        apackA(x, y, z, &Ash[t >> 5][0], t & 31);
    }
    // B-prep chunk 0: 512 threads, one col point each
    bpackB(points, bres, mask, b * NPTS + t, &Bsh[0][t >> 5][0], t & 31);

    // per-batch valid count
    int csum = 0;
    const int4* m4 = (const int4*)(mask + b * NPTS);
#pragma unroll
    for (int r = 0; r < 2; r++) { int4 v = m4[r * 512 + t]; csum += v.x + v.y + v.z + v.w; }
#pragma unroll
    for (int s = 32; s; s >>= 1) csum += __shfl_down(csum, s, 64);
    if (lane == 0) scnt[w] = (float)csum;

    float rm0[16], rm1[16];
#pragma unroll
    for (int r = 0; r < 16; r++) { rm0[r] = 3e38f; rm1[r] = 3e38f; }
    f32x16 zero = {0.f,0.f,0.f,0.f,0.f,0.f,0.f,0.f,0.f,0.f,0.f,0.f,0.f,0.f,0.f,0.f};

    __syncthreads();

    short8 Af0 = ((const short8*)Ash)[(2 * wq + 0) * 64 + lane];
    short8 Af1 = ((const short8*)Ash)[(2 * wq + 1) * 64 + lane];

    for (int c = 0; c < 8; c++) {
        int nb = c & 1;
        if (c < 7)   // compute next chunk's B-frags into the other buffer
            bpackB(points, bres, mask, b * NPTS + (c + 1) * 512 + t,
                   &Bsh[nb ^ 1][t >> 5][0], t & 31);
        const short8* Bt = (const short8*)&Bsh[nb][wh * 8][0];
#pragma unroll
        for (int p = 0; p < 8; p += 2) {
            short8 b0 = Bt[(p + 0) * 64 + lane];
            short8 b1 = Bt[(p + 1) * 64 + lane];
            f32x16 d00 = __builtin_amdgcn_mfma_f32_32x32x16_bf16(Af0, b0, zero, 0, 0, 0);
            f32x16 d01 = __builtin_amdgcn_mfma_f32_32x32x16_bf16(Af0, b1, zero, 0, 0, 0);
#pragma unroll
            for (int r = 0; r < 16; r++)
                rm0[r] = fminf(fminf(rm0[r], d00[r]), d01[r]);   // -> v_min3_f32
            f32x16 d10 = __builtin_amdgcn_mfma_f32_32x32x16_bf16(Af1, b0, zero, 0, 0, 0);
            f32x16 d11 = __builtin_amdgcn_mfma_f32_32x32x16_bf16(Af1, b1, zero, 0, 0, 0);
#pragma unroll
            for (int r = 0; r < 16; r++)
                rm1[r] = fminf(fminf(rm1[r], d10[r]), d11[r]);
        }
        __syncthreads();
    }

    // finalize: col = lane&31 -> reduce across each 32-lane half
#pragma unroll
    for (int r = 0; r < 16; r++) {
#pragma unroll
        for (int s = 1; s <= 16; s <<= 1) {
            rm0[r] = fminf(rm0[r], __shfl_xor(rm0[r], s, 64));
            rm1[r] = fminf(rm1[r], __shfl_xor(rm1[r], s, 64));
        }
    }
    // C/D row = (reg&3) + 8*(reg>>2) + 4*(lane>>5)  [m74/m101-verified]
    if ((lane & 31) == 0) {
        int h = lane >> 5;
        int base = wq * 64 + 4 * h;
#pragma unroll
        for (int r = 0; r < 16; r++) {
            int rr = (r & 3) + 8 * (r >> 2);
            smin[base + rr][wh]      = rm0[r];
            smin[base + 32 + rr][wh] = rm1[r];
        }
    }
    __syncthreads();

    // combine halves, clamp, row-mask, block-reduce
    float part = 0.f;
    if (t < 256) {
        float m = fminf(smin[t][0], smin[t][1]);
        if (mask[b * NPTS + strip * 256 + t]) part = fmaxf(m, 0.f);
    }
#pragma unroll
    for (int s = 32; s; s >>= 1) part += __shfl_down(part, s, 64);
    if (lane == 0) swave[w] = part;
    __syncthreads();
    if (t == 0) {
        float C = 0.f, S = 0.f;
#pragma unroll
        for (int i = 0; i < 8; i++) { C += scnt[i]; S += swave[i]; }
        atomicAdd(out, S / C * 0.125f);
    }
}

extern "C" void kernel_launch(void* const* d_in, const int* in_sizes, int n_in,
                              void* d_out, int out_size, void* d_ws, size_t ws_size,
                              hipStream_t stream) {
    const float* pred   = (const float*)d_in[0];
    const float* target = (const float*)d_in[1];
    const int*   mask   = (const int*)d_in[2];
    const float* points = (const float*)d_in[3];
    float* out = (float*)d_out;

    hipMemsetAsync(out, 0, sizeof(float), stream);   // capturable memset node
    fused_kernel<<<256, 512, 0, stream>>>(pred, target, mask, points, out);
}

// Round 12
// 26.279 us; speedup vs baseline: 1.0344x; 1.0344x over previous
//
#include <hip/hip_runtime.h>

#define NPTS 4096
#define BATCH 8
#define BIGF 1e10f

typedef __attribute__((ext_vector_type(8))) short short8;    // 8 bf16 = 4 VGPR (32x32x16 A/B frag)
typedef __attribute__((ext_vector_type(16))) float f32x16;   // 32x32 C/D frag
typedef unsigned short us;

__device__ __forceinline__ us f2bf(float f) {                // RNE bf16 (unbiased)
    unsigned u = __float_as_uint(f);
    return (us)((u + 0x7FFFu + ((u >> 16) & 1u)) >> 16);
}
__device__ __forceinline__ float bff(us s) { return __uint_as_float(((unsigned)s) << 16); }
__device__ __forceinline__ void split2(float v, us* h, us* m) {
    *h = f2bf(v); *m = f2bf(v - bff(*h));                    // 2-way split, err ~2^-17 |v|
}
__device__ __forceinline__ unsigned pk2(us a, us b) { return (unsigned)a | ((unsigned)b << 16); }

// K=16 pairing (13 live slots, HW-verified absmax ~0 in R10):
//  ak: [thx,thy,thz, thx,thy,thz, tmx,tmy | tmz, x2h,x2m, 1,1, 0,0,0]
//  bk: [bhx,bhy,bhz, bmx,bmy,bmz, bhx,bhy | bhz, 1,1, wh,wm, 0,0,0]
//  dot = x2 + w - 2 x.y  (dropped tm*bm term ~2^-17|2xy|)
__device__ __forceinline__ void apackA(float x, float y, float z,
                                       uint4* __restrict__ dst, int row) {
    const us one = 0x3F80;
    us thx,tmx, thy,tmy, thz,tmz, x2h,x2m;
    split2(-2.f*x, &thx,&tmx);
    split2(-2.f*y, &thy,&tmy);
    split2(-2.f*z, &thz,&tmz);
    split2(x*x + y*y + z*z, &x2h,&x2m);
    dst[row]      = make_uint4(pk2(thx,thy), pk2(thz,thx), pk2(thy,thz), pk2(tmx,tmy));
    dst[row + 32] = make_uint4(pk2(tmz,x2h), pk2(x2m,one), pk2(one,0),   pk2(0,0));
}

__device__ __forceinline__ void bpackB(
    const float* __restrict__ points, const float* __restrict__ bres,
    const int* __restrict__ mask, int g, uint4* __restrict__ dst, int col)
{
    float x = points[g*3+0] + bres[g*3+0];
    float y = points[g*3+1] + bres[g*3+1];
    float z = points[g*3+2] + bres[g*3+2];
    float wq = x*x + y*y + z*z + (mask[g] ? 0.f : BIGF);     // col-side mask penalty
    const us one = 0x3F80;
    us bhx,bmx, bhy,bmy, bhz,bmz, wh,wm;
    split2(x, &bhx,&bmx);
    split2(y, &bhy,&bmy);
    split2(z, &bhz,&bmz);
    split2(wq, &wh,&wm);
    dst[col]      = make_uint4(pk2(bhx,bhy), pk2(bhz,bmx), pk2(bmy,bmz), pk2(bhx,bhy));
    dst[col + 32] = make_uint4(pk2(bhz,one), pk2(one,wh),  pk2(wm,0),    pk2(0,0));
}

// Single fused kernel, 32x32x16 MFMA. Block = (dir, b, 256-row strip);
// 8 waves x 32 rows. Streams 4096 cols in 8 chunks of 512 (16 col-tiles)
// through double-buffered LDS; B-frags computed in-block. One B-frag read
// feeds 1024 outputs. Row-mins in-block -> masked sum -> one atomicAdd
// (out zeroed by memset node).  [R10 configuration -- best measured: 26.4us]
__global__ __launch_bounds__(512, 2) void fused_kernel(
    const float* __restrict__ pred, const float* __restrict__ target,
    const int* __restrict__ mask, const float* __restrict__ points,
    float* __restrict__ out)
{
    __shared__ uint4 Bsh[2][16][64];   // 2 x 16KB: 16 col-tiles
    __shared__ uint4 Ash[8][64];       // 8KB: 8 row-tiles (256 rows)
    __shared__ float scnt[8], swave[8];

    int bid = blockIdx.x;              // 256 = 2 dir x 8 b x 16 strips
    int strip = bid & 15, b = (bid >> 4) & 7, dir = bid >> 7;
    int t = threadIdx.x, w = t >> 6, lane = t & 63;

    const float* __restrict__ ares = dir ? pred : target;    // rows: dir0=clean, dir1=predp
    const float* __restrict__ bres = dir ? target : pred;    // cols: dir0=predp, dir1=clean

    // A-prep: this block's 256 row points (threads 0..255)
    if (t < 256) {
        int g = b * NPTS + strip * 256 + t;
        float x = points[g*3+0] + ares[g*3+0];
        float y = points[g*3+1] + ares[g*3+1];
        float z = points[g*3+2] + ares[g*3+2];
        apackA(x, y, z, &Ash[t >> 5][0], t & 31);
    }
    // B-prep chunk 0: 512 threads, one col point each
    bpackB(points, bres, mask, b * NPTS + t, &Bsh[0][t >> 5][0], t & 31);

    // per-batch valid count
    int csum = 0;
    const int4* m4 = (const int4*)(mask + b * NPTS);
#pragma unroll
    for (int r = 0; r < 2; r++) { int4 v = m4[r * 512 + t]; csum += v.x + v.y + v.z + v.w; }
#pragma unroll
    for (int s = 32; s; s >>= 1) csum += __shfl_down(csum, s, 64);
    if (lane == 0) scnt[w] = (float)csum;

    float rm[16];
#pragma unroll
    for (int r = 0; r < 16; r++) rm[r] = 3e38f;
    f32x16 zero = {0.f,0.f,0.f,0.f,0.f,0.f,0.f,0.f,0.f,0.f,0.f,0.f,0.f,0.f,0.f,0.f};

    __syncthreads();

    short8 Af = ((const short8*)Ash)[w * 64 + lane];   // wave w = row-tile w (32 rows)

    for (int c = 0; c < 8; c++) {
        int nb = c & 1;
        if (c < 7)   // compute next chunk's B-frags into the other buffer
            bpackB(points, bres, mask, b * NPTS + (c + 1) * 512 + t,
                   &Bsh[nb ^ 1][t >> 5][0], t & 31);
        const short8* Bt = (const short8*)&Bsh[nb][0][0];
#pragma unroll
        for (int p = 0; p < 16; p += 2) {
            short8 b0 = Bt[(p + 0) * 64 + lane];
            short8 b1 = Bt[(p + 1) * 64 + lane];
            f32x16 d0 = __builtin_amdgcn_mfma_f32_32x32x16_bf16(Af, b0, zero, 0, 0, 0);
            f32x16 d1 = __builtin_amdgcn_mfma_f32_32x32x16_bf16(Af, b1, zero, 0, 0, 0);
#pragma unroll
            for (int r = 0; r < 16; r++)
                rm[r] = fminf(fminf(rm[r], d0[r]), d1[r]);   // -> v_min3_f32
        }
        __syncthreads();
    }

    // row-min finalize: col = lane&31 -> reduce across the 32-lane half
#pragma unroll
    for (int r = 0; r < 16; r++) {
#pragma unroll
        for (int s = 1; s <= 16; s <<= 1)
            rm[r] = fminf(rm[r], __shfl_xor(rm[r], s, 64));
    }
    // C/D row = (reg&3) + 8*(reg>>2) + 4*(lane>>5)  [m74/m101-verified]
    float part = 0.f;
    if ((lane & 31) == 0) {
        int h = lane >> 5;
        int rowbase = b * NPTS + strip * 256 + w * 32 + 4 * h;
#pragma unroll
        for (int r = 0; r < 16; r++) {
            int row = rowbase + (r & 3) + 8 * (r >> 2);
            if (mask[row]) part += fmaxf(rm[r], 0.f);
        }
    }
    part += __shfl_xor(part, 32, 64);
    if (lane == 0) swave[w] = part;
    __syncthreads();
    if (t == 0) {
        float C = 0.f, S = 0.f;
#pragma unroll
        for (int i = 0; i < 8; i++) { C += scnt[i]; S += swave[i]; }
        atomicAdd(out, S / C * 0.125f);
    }
}

extern "C" void kernel_launch(void* const* d_in, const int* in_sizes, int n_in,
                              void* d_out, int out_size, void* d_ws, size_t ws_size,
                              hipStream_t stream) {
    const float* pred   = (const float*)d_in[0];
    const float* target = (const float*)d_in[1];
    const int*   mask   = (const int*)d_in[2];
    const float* points = (const float*)d_in[3];
    float* out = (float*)d_out;

    hipMemsetAsync(out, 0, sizeof(float), stream);   // capturable memset node
    fused_kernel<<<256, 512, 0, stream>>>(pred, target, mask, points, out);
}